// Round 2
// baseline (2279.832 us; speedup 1.0000x reference)
//
#include <hip/hip_runtime.h>
#include <hip/hip_bf16.h>
#include <stdint.h>

// DbrxExpertGLU: down = (silu(x@w1^T) * (x@v1^T)) @ w2
// T=4096, H=4096, F=14336. fp32 in/out; bf16 MFMA compute.
// Hazard discipline: every ws buffer is single-writer, written before read,
// NEVER rewritten within a launch -> robust to any graph-node/replay overlap.
#define TOKENS 4096
#define HIDDEN 4096
#define FFN    14336

typedef __attribute__((ext_vector_type(8))) short bf16x8;
typedef __attribute__((ext_vector_type(4))) float f32x4;

typedef __attribute__((address_space(3))) void lds_void_t;
typedef const __attribute__((address_space(1))) void gbl_void_t;

__device__ __forceinline__ unsigned short f2b(float f) {
  union { float f; unsigned int u; } v; v.f = f;
  unsigned int u = v.u;
  return (unsigned short)((u + 0x7FFFu + ((u >> 16) & 1u)) >> 16);  // RNE
}

// ---------------- fp32 -> bf16 convert (memory-bound) ----------------
__global__ void cvt_kernel(const float* __restrict__ in, unsigned short* __restrict__ out, long n) {
  long idx = (long)blockIdx.x * blockDim.x + threadIdx.x;
  long stride = (long)gridDim.x * blockDim.x;
  for (long i = idx * 4; i < n; i += stride * 4) {
    const float4 v = *reinterpret_cast<const float4*>(in + i);
    ushort4 o;
    o.x = f2b(v.x); o.y = f2b(v.y); o.z = f2b(v.z); o.w = f2b(v.w);
    *reinterpret_cast<ushort4*>(out + i) = o;
  }
}

// ---------------- GEMM helpers (m97 structure: 128x128 tile, BK=32) ----------------
// Stage a [128][32] bf16 tile into LDS via global_load_lds width=16.
// LDS dest is linear: base + lane*16 per wave-instruction (HW requirement).
__device__ __forceinline__ void stage_tile(const unsigned short* __restrict__ g, long ldk,
                                           unsigned short* lds, int wave, int lane) {
#pragma unroll
  for (int it = 0; it < 2; ++it) {
    const int row = (it * 4 + wave) * 16 + (lane >> 2);
    const int kcol = (lane & 3) * 8;
    const unsigned short* src = g + (long)row * ldk + kcol;
    unsigned short* dst = lds + row * 32 + kcol;   // linear: base + lane*16 bytes
    __builtin_amdgcn_global_load_lds((gbl_void_t*)src, (lds_void_t*)dst, 16, 0, 0);
  }
}

// Fused gate/up GEMM-BT: X[T][H] @ {W1,V1}[F][H]^T -> Inter = silu(gate)*up, bf16 [T][F]
__global__ __launch_bounds__(256, 2)
void gateup_kernel(const unsigned short* __restrict__ X,
                   const unsigned short* __restrict__ W1,
                   const unsigned short* __restrict__ V1,
                   unsigned short* __restrict__ Inter) {
  __shared__ unsigned short As[128 * 32];
  __shared__ unsigned short Ws[128 * 32];
  __shared__ unsigned short Vs[128 * 32];
  const int t = threadIdx.x;
  const int lane = t & 63;
  const int wave = t >> 6;
  const int bn = blockIdx.x % (FFN / 128);
  const int bm = blockIdx.x / (FFN / 128);
  const int wm = (wave >> 1) * 64;
  const int wn = (wave & 1) * 64;
  const unsigned short* gA = X + (long)(bm * 128) * HIDDEN;
  const unsigned short* gW = W1 + (long)(bn * 128) * HIDDEN;
  const unsigned short* gV = V1 + (long)(bn * 128) * HIDDEN;

  f32x4 accg[4][4] = {};
  f32x4 accu[4][4] = {};
  const int fr = lane & 15;        // fragment row/col
  const int kg = (lane >> 4) * 8;  // k-offset

  for (int kt = 0; kt < HIDDEN; kt += 32) {
    __syncthreads();
    stage_tile(gA + kt, HIDDEN, As, wave, lane);
    stage_tile(gW + kt, HIDDEN, Ws, wave, lane);
    stage_tile(gV + kt, HIDDEN, Vs, wave, lane);
    __syncthreads();
    bf16x8 a[4], w[4], v[4];
#pragma unroll
    for (int m = 0; m < 4; ++m)
      a[m] = *reinterpret_cast<const bf16x8*>(&As[(wm + m * 16 + fr) * 32 + kg]);
#pragma unroll
    for (int n = 0; n < 4; ++n) {
      w[n] = *reinterpret_cast<const bf16x8*>(&Ws[(wn + n * 16 + fr) * 32 + kg]);
      v[n] = *reinterpret_cast<const bf16x8*>(&Vs[(wn + n * 16 + fr) * 32 + kg]);
    }
#pragma unroll
    for (int m = 0; m < 4; ++m)
#pragma unroll
      for (int n = 0; n < 4; ++n) {
        accg[m][n] = __builtin_amdgcn_mfma_f32_16x16x32_bf16(a[m], w[n], accg[m][n], 0, 0, 0);
        accu[m][n] = __builtin_amdgcn_mfma_f32_16x16x32_bf16(a[m], v[n], accu[m][n], 0, 0, 0);
      }
  }
  // epilogue: silu(gate)*up -> bf16. C/D map: col=lane&15, row=(lane>>4)*4+reg (m89-verified)
  const int r0 = (lane >> 4) * 4;
#pragma unroll
  for (int m = 0; m < 4; ++m)
#pragma unroll
    for (int n = 0; n < 4; ++n)
#pragma unroll
      for (int r = 0; r < 4; ++r) {
        float g = accg[m][n][r];
        float u = accu[m][n][r];
        float s = g / (1.0f + __expf(-g));
        const int row = bm * 128 + wm + m * 16 + r0 + r;
        const int col = bn * 128 + wn + n * 16 + fr;
        Inter[(long)row * FFN + col] = f2b(s * u);
      }
}

// down GEMM-NT: Inter[T][F] bf16 @ W2[F][H] fp32 -> Out fp32 [T][H]
// B staged with on-the-fly fp32->bf16 transpose into Bs[h][k] (no w2t buffer, no alias).
__global__ __launch_bounds__(256, 2)
void down_nt_kernel(const unsigned short* __restrict__ Inter,
                    const float* __restrict__ W2,
                    float* __restrict__ Out) {
  __shared__ unsigned short As[128 * 32];
  __shared__ unsigned short Bs[128 * 32];   // [h 0..127][k 0..31]
  const int t = threadIdx.x;
  const int lane = t & 63;
  const int wave = t >> 6;
  const int bm = blockIdx.x & 31;   // T-block (inner: consecutive blocks share bn panel)
  const int bn = blockIdx.x >> 5;   // H-block
  const int wm = (wave >> 1) * 64;
  const int wn = (wave & 1) * 64;
  const unsigned short* gA = Inter + (long)(bm * 128) * FFN;

  f32x4 acc[4][4] = {};
  const int fr = lane & 15;
  const int kg = (lane >> 4) * 8;
  // B-staging mapping: k-pair p = lane&15 (k = 2p, 2p+1), h0 = wave*32 + (lane>>4)*8.
  // ds_write_b32 bank = (j&1)*16 + p over lanes -> 16 banks x 4 lanes = 4-way (1.58x, ok).
  const int p = lane & 15;
  const int h0 = wave * 32 + (lane >> 4) * 8;
  const float* gB = W2 + bn * 128 + h0;

  for (int kt = 0; kt < FFN; kt += 32) {
    __syncthreads();
    stage_tile(gA + kt, FFN, As, wave, lane);
    // stage B: rows kt+2p, kt+2p+1 of W2, cols [bn*128+h0, +8), converted to bf16
    const float* r0p = gB + (long)(kt + 2 * p) * HIDDEN;
    const float* r1p = r0p + HIDDEN;
    const float4 a0 = *reinterpret_cast<const float4*>(r0p);
    const float4 a1 = *reinterpret_cast<const float4*>(r0p + 4);
    const float4 b0 = *reinterpret_cast<const float4*>(r1p);
    const float4 b1 = *reinterpret_cast<const float4*>(r1p + 4);
    unsigned short lo[8], hi[8];
    lo[0] = f2b(a0.x); lo[1] = f2b(a0.y); lo[2] = f2b(a0.z); lo[3] = f2b(a0.w);
    lo[4] = f2b(a1.x); lo[5] = f2b(a1.y); lo[6] = f2b(a1.z); lo[7] = f2b(a1.w);
    hi[0] = f2b(b0.x); hi[1] = f2b(b0.y); hi[2] = f2b(b0.z); hi[3] = f2b(b0.w);
    hi[4] = f2b(b1.x); hi[5] = f2b(b1.y); hi[6] = f2b(b1.z); hi[7] = f2b(b1.w);
#pragma unroll
    for (int j = 0; j < 8; ++j) {
      const unsigned int pack = (unsigned int)lo[j] | ((unsigned int)hi[j] << 16);
      *reinterpret_cast<unsigned int*>(&Bs[(h0 + j) * 32 + 2 * p]) = pack;
    }
    __syncthreads();
    bf16x8 a[4], b[4];
#pragma unroll
    for (int m = 0; m < 4; ++m)
      a[m] = *reinterpret_cast<const bf16x8*>(&As[(wm + m * 16 + fr) * 32 + kg]);
#pragma unroll
    for (int n = 0; n < 4; ++n)
      b[n] = *reinterpret_cast<const bf16x8*>(&Bs[(wn + n * 16 + fr) * 32 + kg]);
#pragma unroll
    for (int m = 0; m < 4; ++m)
#pragma unroll
      for (int n = 0; n < 4; ++n)
        acc[m][n] = __builtin_amdgcn_mfma_f32_16x16x32_bf16(a[m], b[n], acc[m][n], 0, 0, 0);
  }
  const int r0 = (lane >> 4) * 4;
#pragma unroll
  for (int m = 0; m < 4; ++m)
#pragma unroll
    for (int n = 0; n < 4; ++n)
#pragma unroll
      for (int r = 0; r < 4; ++r) {
        const int row = bm * 128 + wm + m * 16 + r0 + r;
        const int col = bn * 128 + wn + n * 16 + fr;
        Out[(long)row * HIDDEN + col] = acc[m][n][r];
      }
}

extern "C" void kernel_launch(void* const* d_in, const int* in_sizes, int n_in,
                              void* d_out, int out_size, void* d_ws, size_t ws_size,
                              hipStream_t stream) {
  const float* x  = (const float*)d_in[0];
  const float* w1 = (const float*)d_in[1];
  const float* v1 = (const float*)d_in[2];
  const float* w2 = (const float*)d_in[3];
  float* out = (float*)d_out;

  // ws layout (bytes): xb 33,554,432 | w1b 117,440,512 | v1b 117,440,512 | inter 117,440,512
  // Total 385,875,968. No buffer is ever rewritten or aliased.
  const size_t REQ = 385875968UL;
  if (ws_size < REQ) return;  // fail visibly rather than corrupt
  char* ws = (char*)d_ws;
  unsigned short* xb     = (unsigned short*)(ws);
  unsigned short* w1b    = (unsigned short*)(ws + 33554432L);
  unsigned short* v1b    = (unsigned short*)(ws + 150994944L);
  unsigned short* interb = (unsigned short*)(ws + 268435456L);

  hipLaunchKernelGGL(cvt_kernel, dim3(2048), dim3(256), 0, stream, x,  xb,  (long)TOKENS * HIDDEN);
  hipLaunchKernelGGL(cvt_kernel, dim3(2048), dim3(256), 0, stream, w1, w1b, (long)FFN * HIDDEN);
  hipLaunchKernelGGL(cvt_kernel, dim3(2048), dim3(256), 0, stream, v1, v1b, (long)FFN * HIDDEN);
  hipLaunchKernelGGL(gateup_kernel, dim3((TOKENS / 128) * (FFN / 128)), dim3(256), 0, stream,
                     xb, w1b, v1b, interb);
  hipLaunchKernelGGL(down_nt_kernel, dim3((TOKENS / 128) * (HIDDEN / 128)), dim3(256), 0, stream,
                     interb, w2, out);
}

// Round 3
// 2212.864 us; speedup vs baseline: 1.0303x; 1.0303x over previous
//
#include <hip/hip_runtime.h>
#include <hip/hip_bf16.h>
#include <stdint.h>

// DbrxExpertGLU: down = (silu(x@w1^T) * (x@v1^T)) @ w2
// T=4096, H=4096, F=14336. fp32 in/out; bf16 MFMA compute.
// All ws buffers: single-writer, write-before-read, never rewritten.
#define TOKENS 4096
#define HIDDEN 4096
#define FFN    14336

typedef __attribute__((ext_vector_type(8))) short bf16x8;
typedef __attribute__((ext_vector_type(4))) float f32x4;
typedef __attribute__((ext_vector_type(8))) unsigned short u16x8;

typedef __attribute__((address_space(3))) void lds_void_t;
typedef const __attribute__((address_space(1))) void gbl_void_t;

__device__ __forceinline__ unsigned short f2b(float f) {
  union { float f; unsigned int u; } v; v.f = f;
  unsigned int u = v.u;
  return (unsigned short)((u + 0x7FFFu + ((u >> 16) & 1u)) >> 16);  // RNE
}

// ---------------- fp32 -> bf16 convert (memory-bound) ----------------
__global__ void cvt_kernel(const float* __restrict__ in, unsigned short* __restrict__ out, long n) {
  long idx = (long)blockIdx.x * blockDim.x + threadIdx.x;
  long stride = (long)gridDim.x * blockDim.x;
  for (long i = idx * 4; i < n; i += stride * 4) {
    const float4 v = *reinterpret_cast<const float4*>(in + i);
    ushort4 o;
    o.x = f2b(v.x); o.y = f2b(v.y); o.z = f2b(v.z); o.w = f2b(v.w);
    *reinterpret_cast<ushort4*>(out + i) = o;
  }
}

// ------- w2 [F][H] fp32 -> w2t [H][F] bf16 (tiled transpose+convert) -------
__global__ void transpose_cvt_kernel(const float* __restrict__ in, unsigned short* __restrict__ out) {
  __shared__ float tile[64][65];
  const int f0 = blockIdx.x * 64;   // source row block (F dim)
  const int h0 = blockIdx.y * 64;   // source col block (H dim)
  const int t = threadIdx.x;
  const int rcol = (t & 15) * 4;
  const int rrow = t >> 4;          // 0..15
#pragma unroll
  for (int it = 0; it < 4; ++it) {
    int r = rrow + it * 16;
    const float4 v = *reinterpret_cast<const float4*>(in + (long)(f0 + r) * HIDDEN + h0 + rcol);
    tile[r][rcol] = v.x; tile[r][rcol + 1] = v.y; tile[r][rcol + 2] = v.z; tile[r][rcol + 3] = v.w;
  }
  __syncthreads();
  const int wrow = t >> 2;          // local h 0..63
  const int wc = (t & 3) * 16;      // local f start
  u16x8 lo, hi;
#pragma unroll
  for (int j = 0; j < 8; ++j) lo[j] = f2b(tile[wc + j][wrow]);
#pragma unroll
  for (int j = 0; j < 8; ++j) hi[j] = f2b(tile[wc + 8 + j][wrow]);
  u16x8* dst = reinterpret_cast<u16x8*>(out + (long)(h0 + wrow) * FFN + f0 + wc);
  dst[0] = lo; dst[1] = hi;
}

// ---------------- GEMM helpers (m97 structure: 128x128 tile, BK=32) ----------------
__device__ __forceinline__ void stage_tile(const unsigned short* __restrict__ g, long ldk,
                                           unsigned short* lds, int wave, int lane) {
#pragma unroll
  for (int it = 0; it < 2; ++it) {
    const int row = (it * 4 + wave) * 16 + (lane >> 2);
    const int kcol = (lane & 3) * 8;
    const unsigned short* src = g + (long)row * ldk + kcol;
    unsigned short* dst = lds + row * 32 + kcol;   // linear: base + lane*16 bytes
    __builtin_amdgcn_global_load_lds((gbl_void_t*)src, (lds_void_t*)dst, 16, 0, 0);
  }
}

// T1 XCD swizzle (nwg % 8 == 0): each XCD gets a contiguous chunk
__device__ __forceinline__ int xcd_swz(int orig, int nwg) {
  return (orig & 7) * (nwg >> 3) + (orig >> 3);
}

// Fused gate/up GEMM-BT: X[T][H] @ {W1,V1}[F][H]^T -> Inter = silu(gate)*up, bf16 [T][F]
__global__ __launch_bounds__(256, 2)
void gateup_kernel(const unsigned short* __restrict__ X,
                   const unsigned short* __restrict__ W1,
                   const unsigned short* __restrict__ V1,
                   unsigned short* __restrict__ Inter) {
  __shared__ unsigned short As[128 * 32];
  __shared__ unsigned short Ws[128 * 32];
  __shared__ unsigned short Vs[128 * 32];
  const int t = threadIdx.x;
  const int lane = t & 63;
  const int wave = t >> 6;
  const int swz = xcd_swz(blockIdx.x, (TOKENS / 128) * (FFN / 128));
  const int bn = swz % (FFN / 128);
  const int bm = swz / (FFN / 128);
  const int wm = (wave >> 1) * 64;
  const int wn = (wave & 1) * 64;
  const unsigned short* gA = X + (long)(bm * 128) * HIDDEN;
  const unsigned short* gW = W1 + (long)(bn * 128) * HIDDEN;
  const unsigned short* gV = V1 + (long)(bn * 128) * HIDDEN;

  f32x4 accg[4][4] = {};
  f32x4 accu[4][4] = {};
  const int fr = lane & 15;
  const int kg = (lane >> 4) * 8;

  for (int kt = 0; kt < HIDDEN; kt += 32) {
    __syncthreads();
    stage_tile(gA + kt, HIDDEN, As, wave, lane);
    stage_tile(gW + kt, HIDDEN, Ws, wave, lane);
    stage_tile(gV + kt, HIDDEN, Vs, wave, lane);
    __syncthreads();
    bf16x8 a[4], w[4], v[4];
#pragma unroll
    for (int m = 0; m < 4; ++m)
      a[m] = *reinterpret_cast<const bf16x8*>(&As[(wm + m * 16 + fr) * 32 + kg]);
#pragma unroll
    for (int n = 0; n < 4; ++n) {
      w[n] = *reinterpret_cast<const bf16x8*>(&Ws[(wn + n * 16 + fr) * 32 + kg]);
      v[n] = *reinterpret_cast<const bf16x8*>(&Vs[(wn + n * 16 + fr) * 32 + kg]);
    }
#pragma unroll
    for (int m = 0; m < 4; ++m)
#pragma unroll
      for (int n = 0; n < 4; ++n) {
        accg[m][n] = __builtin_amdgcn_mfma_f32_16x16x32_bf16(a[m], w[n], accg[m][n], 0, 0, 0);
        accu[m][n] = __builtin_amdgcn_mfma_f32_16x16x32_bf16(a[m], v[n], accu[m][n], 0, 0, 0);
      }
  }
  const int r0 = (lane >> 4) * 4;
#pragma unroll
  for (int m = 0; m < 4; ++m)
#pragma unroll
    for (int n = 0; n < 4; ++n)
#pragma unroll
      for (int r = 0; r < 4; ++r) {
        float g = accg[m][n][r];
        float u = accu[m][n][r];
        float s = g / (1.0f + __expf(-g));
        const int row = bm * 128 + wm + m * 16 + r0 + r;
        const int col = bn * 128 + wn + n * 16 + fr;
        Inter[(long)row * FFN + col] = f2b(s * u);
      }
}

// down GEMM-BT: Inter[T][F] bf16 @ W2t[H][F]^T -> Out fp32 [T][H]  (fast path)
__global__ __launch_bounds__(256, 2)
void down_bt_kernel(const unsigned short* __restrict__ Inter,
                    const unsigned short* __restrict__ W2t,
                    float* __restrict__ Out) {
  __shared__ unsigned short As[128 * 32];
  __shared__ unsigned short Bs[128 * 32];
  const int t = threadIdx.x;
  const int lane = t & 63;
  const int wave = t >> 6;
  const int swz = xcd_swz(blockIdx.x, (TOKENS / 128) * (HIDDEN / 128));
  const int bm = swz & 31;          // T-block (inner: consecutive share W2t panel)
  const int bn = swz >> 5;          // H-block
  const int wm = (wave >> 1) * 64;
  const int wn = (wave & 1) * 64;
  const unsigned short* gA = Inter + (long)(bm * 128) * FFN;
  const unsigned short* gB = W2t + (long)(bn * 128) * FFN;

  f32x4 acc[4][4] = {};
  const int fr = lane & 15;
  const int kg = (lane >> 4) * 8;

  for (int kt = 0; kt < FFN; kt += 32) {
    __syncthreads();
    stage_tile(gA + kt, FFN, As, wave, lane);
    stage_tile(gB + kt, FFN, Bs, wave, lane);
    __syncthreads();
    bf16x8 a[4], b[4];
#pragma unroll
    for (int m = 0; m < 4; ++m)
      a[m] = *reinterpret_cast<const bf16x8*>(&As[(wm + m * 16 + fr) * 32 + kg]);
#pragma unroll
    for (int n = 0; n < 4; ++n)
      b[n] = *reinterpret_cast<const bf16x8*>(&Bs[(wn + n * 16 + fr) * 32 + kg]);
#pragma unroll
    for (int m = 0; m < 4; ++m)
#pragma unroll
      for (int n = 0; n < 4; ++n)
        acc[m][n] = __builtin_amdgcn_mfma_f32_16x16x32_bf16(a[m], b[n], acc[m][n], 0, 0, 0);
  }
  const int r0 = (lane >> 4) * 4;
#pragma unroll
  for (int m = 0; m < 4; ++m)
#pragma unroll
    for (int n = 0; n < 4; ++n)
#pragma unroll
      for (int r = 0; r < 4; ++r) {
        const int row = bm * 128 + wm + m * 16 + r0 + r;
        const int col = bn * 128 + wn + n * 16 + fr;
        Out[(long)row * HIDDEN + col] = acc[m][n][r];
      }
}

// down GEMM-NT fallback (round-2 verified): reg-staged fp32 B, no w2t buffer
__global__ __launch_bounds__(256, 2)
void down_nt_kernel(const unsigned short* __restrict__ Inter,
                    const float* __restrict__ W2,
                    float* __restrict__ Out) {
  __shared__ unsigned short As[128 * 32];
  __shared__ unsigned short Bs[128 * 32];
  const int t = threadIdx.x;
  const int lane = t & 63;
  const int wave = t >> 6;
  const int bm = blockIdx.x & 31;
  const int bn = blockIdx.x >> 5;
  const int wm = (wave >> 1) * 64;
  const int wn = (wave & 1) * 64;
  const unsigned short* gA = Inter + (long)(bm * 128) * FFN;

  f32x4 acc[4][4] = {};
  const int fr = lane & 15;
  const int kg = (lane >> 4) * 8;
  const int p = lane & 15;
  const int h0 = wave * 32 + (lane >> 4) * 8;
  const float* gB = W2 + bn * 128 + h0;

  for (int kt = 0; kt < FFN; kt += 32) {
    __syncthreads();
    stage_tile(gA + kt, FFN, As, wave, lane);
    const float* r0p = gB + (long)(kt + 2 * p) * HIDDEN;
    const float* r1p = r0p + HIDDEN;
    const float4 a0 = *reinterpret_cast<const float4*>(r0p);
    const float4 a1 = *reinterpret_cast<const float4*>(r0p + 4);
    const float4 b0 = *reinterpret_cast<const float4*>(r1p);
    const float4 b1 = *reinterpret_cast<const float4*>(r1p + 4);
    unsigned short lo[8], hi[8];
    lo[0] = f2b(a0.x); lo[1] = f2b(a0.y); lo[2] = f2b(a0.z); lo[3] = f2b(a0.w);
    lo[4] = f2b(a1.x); lo[5] = f2b(a1.y); lo[6] = f2b(a1.z); lo[7] = f2b(a1.w);
    hi[0] = f2b(b0.x); hi[1] = f2b(b0.y); hi[2] = f2b(b0.z); hi[3] = f2b(b0.w);
    hi[4] = f2b(b1.x); hi[5] = f2b(b1.y); hi[6] = f2b(b1.z); hi[7] = f2b(b1.w);
#pragma unroll
    for (int j = 0; j < 8; ++j) {
      const unsigned int pack = (unsigned int)lo[j] | ((unsigned int)hi[j] << 16);
      *reinterpret_cast<unsigned int*>(&Bs[(h0 + j) * 32 + 2 * p]) = pack;
    }
    __syncthreads();
    bf16x8 a[4], b[4];
#pragma unroll
    for (int m = 0; m < 4; ++m)
      a[m] = *reinterpret_cast<const bf16x8*>(&As[(wm + m * 16 + fr) * 32 + kg]);
#pragma unroll
    for (int n = 0; n < 4; ++n)
      b[n] = *reinterpret_cast<const bf16x8*>(&Bs[(wn + n * 16 + fr) * 32 + kg]);
#pragma unroll
    for (int m = 0; m < 4; ++m)
#pragma unroll
      for (int n = 0; n < 4; ++n)
        acc[m][n] = __builtin_amdgcn_mfma_f32_16x16x32_bf16(a[m], b[n], acc[m][n], 0, 0, 0);
  }
  const int r0 = (lane >> 4) * 4;
#pragma unroll
  for (int m = 0; m < 4; ++m)
#pragma unroll
    for (int n = 0; n < 4; ++n)
#pragma unroll
      for (int r = 0; r < 4; ++r) {
        const int row = bm * 128 + wm + m * 16 + r0 + r;
        const int col = bn * 128 + wn + n * 16 + fr;
        Out[(long)row * HIDDEN + col] = acc[m][n][r];
      }
}

extern "C" void kernel_launch(void* const* d_in, const int* in_sizes, int n_in,
                              void* d_out, int out_size, void* d_ws, size_t ws_size,
                              hipStream_t stream) {
  const float* x  = (const float*)d_in[0];
  const float* w1 = (const float*)d_in[1];
  const float* v1 = (const float*)d_in[2];
  const float* w2 = (const float*)d_in[3];
  float* out = (float*)d_out;

  // ws layout (bytes): xb 33,554,432 | w1b 117,440,512 | v1b 117,440,512 |
  //                    inter 117,440,512 | w2t 117,440,512  -> 503,316,480 total.
  const size_t REQ_SMALL = 385875968UL;   // without w2t (fallback)
  const size_t REQ_FULL  = 503316480UL;   // with dedicated w2t
  if (ws_size < REQ_SMALL) return;  // fail visibly rather than corrupt
  const bool full = (ws_size >= REQ_FULL);
  char* ws = (char*)d_ws;
  unsigned short* xb     = (unsigned short*)(ws);
  unsigned short* w1b    = (unsigned short*)(ws + 33554432L);
  unsigned short* v1b    = (unsigned short*)(ws + 150994944L);
  unsigned short* interb = (unsigned short*)(ws + 268435456L);
  unsigned short* w2tb   = (unsigned short*)(ws + 385875968L);

  hipLaunchKernelGGL(cvt_kernel, dim3(2048), dim3(256), 0, stream, x,  xb,  (long)TOKENS * HIDDEN);
  hipLaunchKernelGGL(cvt_kernel, dim3(2048), dim3(256), 0, stream, w1, w1b, (long)FFN * HIDDEN);
  hipLaunchKernelGGL(cvt_kernel, dim3(2048), dim3(256), 0, stream, v1, v1b, (long)FFN * HIDDEN);
  if (full)
    hipLaunchKernelGGL(transpose_cvt_kernel, dim3(FFN / 64, HIDDEN / 64), dim3(256), 0, stream, w2, w2tb);
  hipLaunchKernelGGL(gateup_kernel, dim3((TOKENS / 128) * (FFN / 128)), dim3(256), 0, stream,
                     xb, w1b, v1b, interb);
  if (full)
    hipLaunchKernelGGL(down_bt_kernel, dim3((TOKENS / 128) * (HIDDEN / 128)), dim3(256), 0, stream,
                       interb, w2tb, out);
  else
    hipLaunchKernelGGL(down_nt_kernel, dim3((TOKENS / 128) * (HIDDEN / 128)), dim3(256), 0, stream,
                       interb, w2, out);
}

// Round 4
// 1898.882 us; speedup vs baseline: 1.2006x; 1.1654x over previous
//
#include <hip/hip_runtime.h>
#include <hip/hip_bf16.h>
#include <stdint.h>

// DbrxExpertGLU: down = (silu(x@w1^T) * (x@v1^T)) @ w2
// T=4096, H=4096, F=14336. fp32 in/out; bf16 MFMA compute.
// All ws buffers: single-writer, write-before-read, never rewritten.
#define TOKENS 4096
#define HIDDEN 4096
#define FFN    14336

typedef __attribute__((ext_vector_type(8))) short bf16x8;
typedef __attribute__((ext_vector_type(4))) float f32x4;
typedef __attribute__((ext_vector_type(8))) unsigned short u16x8;

typedef __attribute__((address_space(3))) void lds_void_t;
typedef const __attribute__((address_space(1))) void gbl_void_t;

__device__ __forceinline__ unsigned short f2b(float f) {
  union { float f; unsigned int u; } v; v.f = f;
  unsigned int u = v.u;
  return (unsigned short)((u + 0x7FFFu + ((u >> 16) & 1u)) >> 16);  // RNE
}

// ---------------- fp32 -> bf16 convert (memory-bound) ----------------
__global__ void cvt_kernel(const float* __restrict__ in, unsigned short* __restrict__ out, long n) {
  long idx = (long)blockIdx.x * blockDim.x + threadIdx.x;
  long stride = (long)gridDim.x * blockDim.x;
  for (long i = idx * 4; i < n; i += stride * 4) {
    const float4 v = *reinterpret_cast<const float4*>(in + i);
    ushort4 o;
    o.x = f2b(v.x); o.y = f2b(v.y); o.z = f2b(v.z); o.w = f2b(v.w);
    *reinterpret_cast<ushort4*>(out + i) = o;
  }
}

// ------- w2 [F][H] fp32 -> w2t [H][F] bf16 (tiled transpose+convert) -------
__global__ void transpose_cvt_kernel(const float* __restrict__ in, unsigned short* __restrict__ out) {
  __shared__ float tile[64][65];
  const int f0 = blockIdx.x * 64;   // source row block (F dim)
  const int h0 = blockIdx.y * 64;   // source col block (H dim)
  const int t = threadIdx.x;
  const int rcol = (t & 15) * 4;
  const int rrow = t >> 4;          // 0..15
#pragma unroll
  for (int it = 0; it < 4; ++it) {
    int r = rrow + it * 16;
    const float4 v = *reinterpret_cast<const float4*>(in + (long)(f0 + r) * HIDDEN + h0 + rcol);
    tile[r][rcol] = v.x; tile[r][rcol + 1] = v.y; tile[r][rcol + 2] = v.z; tile[r][rcol + 3] = v.w;
  }
  __syncthreads();
  const int wrow = t >> 2;          // local h 0..63
  const int wc = (t & 3) * 16;      // local f start
  u16x8 lo, hi;
#pragma unroll
  for (int j = 0; j < 8; ++j) lo[j] = f2b(tile[wc + j][wrow]);
#pragma unroll
  for (int j = 0; j < 8; ++j) hi[j] = f2b(tile[wc + 8 + j][wrow]);
  u16x8* dst = reinterpret_cast<u16x8*>(out + (long)(h0 + wrow) * FFN + f0 + wc);
  dst[0] = lo; dst[1] = hi;
}

// ---------------- GEMM helpers (m97 structure: 128x128 tile, BK=32) ----------------
__device__ __forceinline__ void stage_tile(const unsigned short* __restrict__ g, long ldk,
                                           unsigned short* lds, int wave, int lane) {
#pragma unroll
  for (int it = 0; it < 2; ++it) {
    const int row = (it * 4 + wave) * 16 + (lane >> 2);
    const int kcol = (lane & 3) * 8;
    const unsigned short* src = g + (long)row * ldk + kcol;
    unsigned short* dst = lds + row * 32 + kcol;   // linear: base + lane*16 bytes
    __builtin_amdgcn_global_load_lds((gbl_void_t*)src, (lds_void_t*)dst, 16, 0, 0);
  }
}

// T1 XCD swizzle (nwg % 8 == 0): each XCD gets a contiguous chunk
__device__ __forceinline__ int xcd_swz(int orig, int nwg) {
  return (orig & 7) * (nwg >> 3) + (orig >> 3);
}

// Fused gate/up GEMM-BT: X[T][H] @ {W1,V1}[F][H]^T -> Inter = silu(gate)*up, bf16 [T][F]
// Tile order: bm (token dim) fastest -> concurrent blocks span ~16 bn cols x 32 bm rows;
// live weight working set ~32MB + A 32MB, both L3-resident; weights stream from HBM once.
__global__ __launch_bounds__(256, 2)
void gateup_kernel(const unsigned short* __restrict__ X,
                   const unsigned short* __restrict__ W1,
                   const unsigned short* __restrict__ V1,
                   unsigned short* __restrict__ Inter) {
  __shared__ unsigned short As[128 * 32];
  __shared__ unsigned short Ws[128 * 32];
  __shared__ unsigned short Vs[128 * 32];
  const int t = threadIdx.x;
  const int lane = t & 63;
  const int wave = t >> 6;
  const int bm = blockIdx.x & 31;   // T-block: FASTEST
  const int bn = blockIdx.x >> 5;   // F-block
  const int wm = (wave >> 1) * 64;
  const int wn = (wave & 1) * 64;
  const unsigned short* gA = X + (long)(bm * 128) * HIDDEN;
  const unsigned short* gW = W1 + (long)(bn * 128) * HIDDEN;
  const unsigned short* gV = V1 + (long)(bn * 128) * HIDDEN;

  f32x4 accg[4][4] = {};
  f32x4 accu[4][4] = {};
  const int fr = lane & 15;
  const int kg = (lane >> 4) * 8;

  for (int kt = 0; kt < HIDDEN; kt += 32) {
    __syncthreads();
    stage_tile(gA + kt, HIDDEN, As, wave, lane);
    stage_tile(gW + kt, HIDDEN, Ws, wave, lane);
    stage_tile(gV + kt, HIDDEN, Vs, wave, lane);
    __syncthreads();
    bf16x8 a[4], w[4], v[4];
#pragma unroll
    for (int m = 0; m < 4; ++m)
      a[m] = *reinterpret_cast<const bf16x8*>(&As[(wm + m * 16 + fr) * 32 + kg]);
#pragma unroll
    for (int n = 0; n < 4; ++n) {
      w[n] = *reinterpret_cast<const bf16x8*>(&Ws[(wn + n * 16 + fr) * 32 + kg]);
      v[n] = *reinterpret_cast<const bf16x8*>(&Vs[(wn + n * 16 + fr) * 32 + kg]);
    }
#pragma unroll
    for (int m = 0; m < 4; ++m)
#pragma unroll
      for (int n = 0; n < 4; ++n) {
        accg[m][n] = __builtin_amdgcn_mfma_f32_16x16x32_bf16(a[m], w[n], accg[m][n], 0, 0, 0);
        accu[m][n] = __builtin_amdgcn_mfma_f32_16x16x32_bf16(a[m], v[n], accu[m][n], 0, 0, 0);
      }
  }
  const int r0 = (lane >> 4) * 4;
#pragma unroll
  for (int m = 0; m < 4; ++m)
#pragma unroll
    for (int n = 0; n < 4; ++n)
#pragma unroll
      for (int r = 0; r < 4; ++r) {
        float g = accg[m][n][r];
        float u = accu[m][n][r];
        float s = g / (1.0f + __expf(-g));
        const int row = bm * 128 + wm + m * 16 + r0 + r;
        const int col = bn * 128 + wn + n * 16 + fr;
        Inter[(long)row * FFN + col] = f2b(s * u);
      }
}

// down GEMM-BT: Inter[T][F] bf16 @ W2t[H][F]^T -> Out fp32 [T][H]  (fast path)
__global__ __launch_bounds__(256, 2)
void down_bt_kernel(const unsigned short* __restrict__ Inter,
                    const unsigned short* __restrict__ W2t,
                    float* __restrict__ Out) {
  __shared__ unsigned short As[128 * 32];
  __shared__ unsigned short Bs[128 * 32];
  const int t = threadIdx.x;
  const int lane = t & 63;
  const int wave = t >> 6;
  const int swz = xcd_swz(blockIdx.x, (TOKENS / 128) * (HIDDEN / 128));
  const int bm = swz & 31;          // T-block fastest within chunk
  const int bn = swz >> 5;          // H-block
  const int wm = (wave >> 1) * 64;
  const int wn = (wave & 1) * 64;
  const unsigned short* gA = Inter + (long)(bm * 128) * FFN;
  const unsigned short* gB = W2t + (long)(bn * 128) * FFN;

  f32x4 acc[4][4] = {};
  const int fr = lane & 15;
  const int kg = (lane >> 4) * 8;

  for (int kt = 0; kt < FFN; kt += 32) {
    __syncthreads();
    stage_tile(gA + kt, FFN, As, wave, lane);
    stage_tile(gB + kt, FFN, Bs, wave, lane);
    __syncthreads();
    bf16x8 a[4], b[4];
#pragma unroll
    for (int m = 0; m < 4; ++m)
      a[m] = *reinterpret_cast<const bf16x8*>(&As[(wm + m * 16 + fr) * 32 + kg]);
#pragma unroll
    for (int n = 0; n < 4; ++n)
      b[n] = *reinterpret_cast<const bf16x8*>(&Bs[(wn + n * 16 + fr) * 32 + kg]);
#pragma unroll
    for (int m = 0; m < 4; ++m)
#pragma unroll
      for (int n = 0; n < 4; ++n)
        acc[m][n] = __builtin_amdgcn_mfma_f32_16x16x32_bf16(a[m], b[n], acc[m][n], 0, 0, 0);
  }
  const int r0 = (lane >> 4) * 4;
#pragma unroll
  for (int m = 0; m < 4; ++m)
#pragma unroll
    for (int n = 0; n < 4; ++n)
#pragma unroll
      for (int r = 0; r < 4; ++r) {
        const int row = bm * 128 + wm + m * 16 + r0 + r;
        const int col = bn * 128 + wn + n * 16 + fr;
        Out[(long)row * HIDDEN + col] = acc[m][n][r];
      }
}

// down GEMM-NT fallback (round-2 verified): reg-staged fp32 B, no w2t buffer
__global__ __launch_bounds__(256, 2)
void down_nt_kernel(const unsigned short* __restrict__ Inter,
                    const float* __restrict__ W2,
                    float* __restrict__ Out) {
  __shared__ unsigned short As[128 * 32];
  __shared__ unsigned short Bs[128 * 32];
  const int t = threadIdx.x;
  const int lane = t & 63;
  const int wave = t >> 6;
  const int bm = blockIdx.x & 31;
  const int bn = blockIdx.x >> 5;
  const int wm = (wave >> 1) * 64;
  const int wn = (wave & 1) * 64;
  const unsigned short* gA = Inter + (long)(bm * 128) * FFN;

  f32x4 acc[4][4] = {};
  const int fr = lane & 15;
  const int kg = (lane >> 4) * 8;
  const int p = lane & 15;
  const int h0 = wave * 32 + (lane >> 4) * 8;
  const float* gB = W2 + bn * 128 + h0;

  for (int kt = 0; kt < FFN; kt += 32) {
    __syncthreads();
    stage_tile(gA + kt, FFN, As, wave, lane);
    const float* r0p = gB + (long)(kt + 2 * p) * HIDDEN;
    const float* r1p = r0p + HIDDEN;
    const float4 a0 = *reinterpret_cast<const float4*>(r0p);
    const float4 a1 = *reinterpret_cast<const float4*>(r0p + 4);
    const float4 b0 = *reinterpret_cast<const float4*>(r1p);
    const float4 b1 = *reinterpret_cast<const float4*>(r1p + 4);
    unsigned short lo[8], hi[8];
    lo[0] = f2b(a0.x); lo[1] = f2b(a0.y); lo[2] = f2b(a0.z); lo[3] = f2b(a0.w);
    lo[4] = f2b(a1.x); lo[5] = f2b(a1.y); lo[6] = f2b(a1.z); lo[7] = f2b(a1.w);
    hi[0] = f2b(b0.x); hi[1] = f2b(b0.y); hi[2] = f2b(b0.z); hi[3] = f2b(b0.w);
    hi[4] = f2b(b1.x); hi[5] = f2b(b1.y); hi[6] = f2b(b1.z); hi[7] = f2b(b1.w);
#pragma unroll
    for (int j = 0; j < 8; ++j) {
      const unsigned int pack = (unsigned int)lo[j] | ((unsigned int)hi[j] << 16);
      *reinterpret_cast<unsigned int*>(&Bs[(h0 + j) * 32 + 2 * p]) = pack;
    }
    __syncthreads();
    bf16x8 a[4], b[4];
#pragma unroll
    for (int m = 0; m < 4; ++m)
      a[m] = *reinterpret_cast<const bf16x8*>(&As[(wm + m * 16 + fr) * 32 + kg]);
#pragma unroll
    for (int n = 0; n < 4; ++n)
      b[n] = *reinterpret_cast<const bf16x8*>(&Bs[(wn + n * 16 + fr) * 32 + kg]);
#pragma unroll
    for (int m = 0; m < 4; ++m)
#pragma unroll
      for (int n = 0; n < 4; ++n)
        acc[m][n] = __builtin_amdgcn_mfma_f32_16x16x32_bf16(a[m], b[n], acc[m][n], 0, 0, 0);
  }
  const int r0 = (lane >> 4) * 4;
#pragma unroll
  for (int m = 0; m < 4; ++m)
#pragma unroll
    for (int n = 0; n < 4; ++n)
#pragma unroll
      for (int r = 0; r < 4; ++r) {
        const int row = bm * 128 + wm + m * 16 + r0 + r;
        const int col = bn * 128 + wn + n * 16 + fr;
        Out[(long)row * HIDDEN + col] = acc[m][n][r];
      }
}

extern "C" void kernel_launch(void* const* d_in, const int* in_sizes, int n_in,
                              void* d_out, int out_size, void* d_ws, size_t ws_size,
                              hipStream_t stream) {
  const float* x  = (const float*)d_in[0];
  const float* w1 = (const float*)d_in[1];
  const float* v1 = (const float*)d_in[2];
  const float* w2 = (const float*)d_in[3];
  float* out = (float*)d_out;

  // ws layout (bytes): xb 33,554,432 | w1b 117,440,512 | v1b 117,440,512 |
  //                    inter 117,440,512 | w2t 117,440,512  -> 503,316,480 total.
  const size_t REQ_SMALL = 385875968UL;   // without w2t (fallback)
  const size_t REQ_FULL  = 503316480UL;   // with dedicated w2t
  if (ws_size < REQ_SMALL) return;  // fail visibly rather than corrupt
  const bool full = (ws_size >= REQ_FULL);
  char* ws = (char*)d_ws;
  unsigned short* xb     = (unsigned short*)(ws);
  unsigned short* w1b    = (unsigned short*)(ws + 33554432L);
  unsigned short* v1b    = (unsigned short*)(ws + 150994944L);
  unsigned short* interb = (unsigned short*)(ws + 268435456L);
  unsigned short* w2tb   = (unsigned short*)(ws + 385875968L);

  hipLaunchKernelGGL(cvt_kernel, dim3(2048), dim3(256), 0, stream, x,  xb,  (long)TOKENS * HIDDEN);
  hipLaunchKernelGGL(cvt_kernel, dim3(2048), dim3(256), 0, stream, w1, w1b, (long)FFN * HIDDEN);
  hipLaunchKernelGGL(cvt_kernel, dim3(2048), dim3(256), 0, stream, v1, v1b, (long)FFN * HIDDEN);
  if (full)
    hipLaunchKernelGGL(transpose_cvt_kernel, dim3(FFN / 64, HIDDEN / 64), dim3(256), 0, stream, w2, w2tb);
  hipLaunchKernelGGL(gateup_kernel, dim3((TOKENS / 128) * (FFN / 128)), dim3(256), 0, stream,
                     xb, w1b, v1b, interb);
  if (full)
    hipLaunchKernelGGL(down_bt_kernel, dim3((TOKENS / 128) * (HIDDEN / 128)), dim3(256), 0, stream,
                       interb, w2tb, out);
  else
    hipLaunchKernelGGL(down_nt_kernel, dim3((TOKENS / 128) * (HIDDEN / 128)), dim3(256), 0, stream,
                       interb, w2, out);
}

// Round 5
// 1476.073 us; speedup vs baseline: 1.5445x; 1.2864x over previous
//
#include <hip/hip_runtime.h>
#include <hip/hip_bf16.h>
#include <stdint.h>

// DbrxExpertGLU: down = (silu(x@w1^T) * (x@v1^T)) @ w2
// T=4096, H=4096, F=14336. fp32 in/out; bf16 MFMA compute.
// GEMMs use the 256-tile 8-phase counted-vmcnt schedule (T2+T3+T4+T5).
// All ws buffers: single-writer, write-before-read, never rewritten.
#define TOKENS 4096
#define HIDDEN 4096
#define FFN    14336

typedef __attribute__((ext_vector_type(8))) short bf16x8;
typedef __attribute__((ext_vector_type(4))) float f32x4;
typedef __attribute__((ext_vector_type(8))) unsigned short u16x8;

typedef __attribute__((address_space(3))) void lds_void_t;
typedef const __attribute__((address_space(1))) void gbl_void_t;

static __device__ __forceinline__ unsigned short f2b(float f) {
  union { float f; unsigned int u; } v; v.f = f;
  unsigned int u = v.u;
  return (unsigned short)((u + 0x7FFFu + ((u >> 16) & 1u)) >> 16);  // RNE
}

// ---------------- fp32 -> bf16 convert ----------------
__global__ void cvt_kernel(const float* __restrict__ in, unsigned short* __restrict__ out, long n) {
  long idx = (long)blockIdx.x * blockDim.x + threadIdx.x;
  long stride = (long)gridDim.x * blockDim.x;
  for (long i = idx * 4; i < n; i += stride * 4) {
    const float4 v = *reinterpret_cast<const float4*>(in + i);
    ushort4 o;
    o.x = f2b(v.x); o.y = f2b(v.y); o.z = f2b(v.z); o.w = f2b(v.w);
    *reinterpret_cast<ushort4*>(out + i) = o;
  }
}

// ------- w2 [F][H] fp32 -> w2t [H][F] bf16 -------
__global__ void transpose_cvt_kernel(const float* __restrict__ in, unsigned short* __restrict__ out) {
  __shared__ float tile[64][65];
  const int f0 = blockIdx.x * 64;
  const int h0 = blockIdx.y * 64;
  const int t = threadIdx.x;
  const int rcol = (t & 15) * 4;
  const int rrow = t >> 4;
#pragma unroll
  for (int it = 0; it < 4; ++it) {
    int r = rrow + it * 16;
    const float4 v = *reinterpret_cast<const float4*>(in + (long)(f0 + r) * HIDDEN + h0 + rcol);
    tile[r][rcol] = v.x; tile[r][rcol + 1] = v.y; tile[r][rcol + 2] = v.z; tile[r][rcol + 3] = v.w;
  }
  __syncthreads();
  const int wrow = t >> 2;
  const int wc = (t & 3) * 16;
  u16x8 lo, hi;
#pragma unroll
  for (int j = 0; j < 8; ++j) lo[j] = f2b(tile[wc + j][wrow]);
#pragma unroll
  for (int j = 0; j < 8; ++j) hi[j] = f2b(tile[wc + 8 + j][wrow]);
  u16x8* dst = reinterpret_cast<u16x8*>(out + (long)(h0 + wrow) * FFN + f0 + wc);
  dst[0] = lo; dst[1] = hi;
}

#define MFMA16(a, b, c) __builtin_amdgcn_mfma_f32_16x16x32_bf16((a), (b), (c), 0, 0, 0)

// ============ fused gate/up, 8-phase: BM=256(T) x BN=128(F), BK=64, 8 waves ============
// LDS per buf (64KB): A[256][64] @0 | W[128][64] @32K | V[128][64] @48K.  x2 dbuf = 128KB.
// Swizzle: byte_in_row ^= ((row&7)<<4); gload_lds dest linear, SOURCE pre-swizzled (rule #21).
__global__ __launch_bounds__(512, 2)
void gateup256_kernel(const unsigned short* __restrict__ X,
                      const unsigned short* __restrict__ W1,
                      const unsigned short* __restrict__ V1,
                      unsigned short* __restrict__ Inter) {
  __shared__ unsigned short sh[65536];  // 128 KB
  const int tid = threadIdx.x, lane = tid & 63, wid = tid >> 6;
  const int wm = wid >> 2, wn = wid & 3;
  const int bm = blockIdx.x & 15;   // T-tile fastest (L2/L3 weight-panel reuse)
  const int bn = blockIdx.x >> 4;   // F-tile
  const int sr = tid >> 3;                                   // staging row 0..63
  const int scb = (((tid & 7) ^ (sr & 7)) << 4);             // pre-swizzled src byte-col
  const int l15 = lane & 15;
  const int cb0 = (((lane >> 4) * 16) ^ ((lane & 7) << 4));  // frag byte-col, kk=0
  const int cb1 = ((64 + (lane >> 4) * 16) ^ ((lane & 7) << 4));

  const unsigned short* Ap = X  + (long)(bm * 256) * HIDDEN;
  const unsigned short* Wp = W1 + (long)(bn * 128) * HIDDEN;
  const unsigned short* Vp = V1 + (long)(bn * 128) * HIDDEN;

  f32x4 accg[8][2] = {};
  f32x4 accu[8][2] = {};

  auto STA = [&](int u, int buf, int t) {  // A unit u: rows u*64..+63, 8KB, 1 gload/thread
    const unsigned short* src = Ap + (long)(u * 64 + sr) * HIDDEN + t * 64 + (scb >> 1);
    unsigned short* dst = sh + buf * 32768 + u * 4096 + tid * 8;
    __builtin_amdgcn_global_load_lds((gbl_void_t*)src, (lds_void_t*)dst, 16, 0, 0);
  };
  auto STW = [&](int u, int buf, int t) {
    const unsigned short* src = Wp + (long)(u * 64 + sr) * HIDDEN + t * 64 + (scb >> 1);
    unsigned short* dst = sh + buf * 32768 + 16384 + u * 4096 + tid * 8;
    __builtin_amdgcn_global_load_lds((gbl_void_t*)src, (lds_void_t*)dst, 16, 0, 0);
  };
  auto STV = [&](int u, int buf, int t) {
    const unsigned short* src = Vp + (long)(u * 64 + sr) * HIDDEN + t * 64 + (scb >> 1);
    unsigned short* dst = sh + buf * 32768 + 24576 + u * 4096 + tid * 8;
    __builtin_amdgcn_global_load_lds((gbl_void_t*)src, (lds_void_t*)dst, 16, 0, 0);
  };
  auto LDA8 = [&](bf16x8* a, int buf, int cb) {
    const char* base = (const char*)sh + buf * 65536 + wm * 16384 + l15 * 128 + cb;
#pragma unroll
    for (int m = 0; m < 8; ++m) a[m] = *(const bf16x8*)(base + m * 2048);
  };
  auto LDW2 = [&](bf16x8* w, int buf, int cb) {
    const char* base = (const char*)sh + buf * 65536 + 32768 + (wn * 32 + l15) * 128 + cb;
    w[0] = *(const bf16x8*)(base);
    w[1] = *(const bf16x8*)(base + 2048);
  };
  auto LDV2 = [&](bf16x8* v, int buf, int cb) {
    const char* base = (const char*)sh + buf * 65536 + 49152 + (wn * 32 + l15) * 128 + cb;
    v[0] = *(const bf16x8*)(base);
    v[1] = *(const bf16x8*)(base + 2048);
  };

  // prologue: tile 0 fully staged into buf0 (8 loads/thread)
  STA(0, 0, 0); STA(1, 0, 0); STA(2, 0, 0); STA(3, 0, 0);
  STW(0, 0, 0); STW(1, 0, 0); STV(0, 0, 0); STV(1, 0, 0);

  bf16x8 a[8], w[2], v[2];
  const int NT = HIDDEN / 64;  // 64
  for (int t = 0; t < NT; ++t) {
    const int cur = t & 1, nxt = cur ^ 1;
    const bool pre = (t + 1 < NT);
    // ---- phase 0: prefetch A0,A1(t+1); gate; kk0 x W
    if (pre) { STA(0, nxt, t + 1); STA(1, nxt, t + 1);
               asm volatile("s_waitcnt vmcnt(2)" ::: "memory"); }
    else     { asm volatile("s_waitcnt vmcnt(0)" ::: "memory"); }
    __builtin_amdgcn_s_barrier();
    __builtin_amdgcn_sched_barrier(0);
    LDA8(a, cur, cb0); LDW2(w, cur, cb0);
    __builtin_amdgcn_s_setprio(1);
#pragma unroll
    for (int m = 0; m < 8; ++m) {
      accg[m][0] = MFMA16(a[m], w[0], accg[m][0]);
      accg[m][1] = MFMA16(a[m], w[1], accg[m][1]);
    }
    __builtin_amdgcn_s_setprio(0);
    __builtin_amdgcn_sched_barrier(0);
    asm volatile("s_waitcnt lgkmcnt(0)" ::: "memory");
    __builtin_amdgcn_s_barrier();
    // ---- phase 1: prefetch A2,A3(t+1); kk0 x V
    if (pre) { STA(2, nxt, t + 1); STA(3, nxt, t + 1); }
    __builtin_amdgcn_sched_barrier(0);
    LDV2(v, cur, cb0);
    __builtin_amdgcn_s_setprio(1);
#pragma unroll
    for (int m = 0; m < 8; ++m) {
      accu[m][0] = MFMA16(a[m], v[0], accu[m][0]);
      accu[m][1] = MFMA16(a[m], v[1], accu[m][1]);
    }
    __builtin_amdgcn_s_setprio(0);
    __builtin_amdgcn_sched_barrier(0);
    asm volatile("s_waitcnt lgkmcnt(0)" ::: "memory");
    __builtin_amdgcn_s_barrier();
    // ---- phase 2: prefetch W0,W1(t+1); kk1 x W
    if (pre) { STW(0, nxt, t + 1); STW(1, nxt, t + 1); }
    __builtin_amdgcn_sched_barrier(0);
    LDA8(a, cur, cb1); LDW2(w, cur, cb1);
    __builtin_amdgcn_s_setprio(1);
#pragma unroll
    for (int m = 0; m < 8; ++m) {
      accg[m][0] = MFMA16(a[m], w[0], accg[m][0]);
      accg[m][1] = MFMA16(a[m], w[1], accg[m][1]);
    }
    __builtin_amdgcn_s_setprio(0);
    __builtin_amdgcn_sched_barrier(0);
    asm volatile("s_waitcnt lgkmcnt(0)" ::: "memory");
    __builtin_amdgcn_s_barrier();
    // ---- phase 3: prefetch V0,V1(t+1); kk1 x V
    if (pre) { STV(0, nxt, t + 1); STV(1, nxt, t + 1); }
    __builtin_amdgcn_sched_barrier(0);
    LDV2(v, cur, cb1);
    __builtin_amdgcn_s_setprio(1);
#pragma unroll
    for (int m = 0; m < 8; ++m) {
      accu[m][0] = MFMA16(a[m], v[0], accu[m][0]);
      accu[m][1] = MFMA16(a[m], v[1], accu[m][1]);
    }
    __builtin_amdgcn_s_setprio(0);
    __builtin_amdgcn_sched_barrier(0);
    asm volatile("s_waitcnt lgkmcnt(0)" ::: "memory");
    __builtin_amdgcn_s_barrier();
  }
  // epilogue: silu(g)*u -> bf16. C/D map: col=lane&15, row=(lane>>4)*4+r (m89)
  const int r0 = (lane >> 4) * 4;
#pragma unroll
  for (int m = 0; m < 8; ++m)
#pragma unroll
    for (int n = 0; n < 2; ++n)
#pragma unroll
      for (int r = 0; r < 4; ++r) {
        const float g = accg[m][n][r];
        const float u = accu[m][n][r];
        const float s = g / (1.0f + __expf(-g));
        const int row = bm * 256 + wm * 128 + m * 16 + r0 + r;
        const int col = bn * 128 + wn * 32 + n * 16 + l15;
        Inter[(long)row * FFN + col] = f2b(s * u);
      }
}

// ============ down GEMM-BT, 8-phase: 256x256, BK=64, 8 waves ============
// LDS per buf (64KB): A 2 halves [128][64] @0,@16K | B 2 halves @32K,@48K. x2 = 128KB.
__global__ __launch_bounds__(512, 2)
void down256_kernel(const unsigned short* __restrict__ Inter,
                    const unsigned short* __restrict__ W2t,
                    float* __restrict__ Out) {
  __shared__ unsigned short sh[65536];
  const int tid = threadIdx.x, lane = tid & 63, wid = tid >> 6;
  const int wm = wid >> 2, wn = wid & 3;
  const int bm = blockIdx.x & 15;   // T-tile fastest
  const int bn = blockIdx.x >> 4;   // H-tile
  const int sr = tid >> 3;
  const int scb = (((tid & 7) ^ (sr & 7)) << 4);
  const int l15 = lane & 15;
  const int cb0 = (((lane >> 4) * 16) ^ ((lane & 7) << 4));
  const int cb1 = ((64 + (lane >> 4) * 16) ^ ((lane & 7) << 4));

  const unsigned short* Ap = Inter + (long)(bm * 256) * FFN;
  const unsigned short* Bp = W2t + (long)(bn * 256) * FFN;

  f32x4 acc[8][4] = {};

  auto STAGE = [&](int kind, int h, int buf, int t) {  // half h: 128 rows, 2 gloads/thread
    const unsigned short* src = (kind ? Bp : Ap) + (long)(h * 128 + sr) * FFN + t * 64 + (scb >> 1);
    unsigned short* dst = sh + buf * 32768 + kind * 16384 + h * 8192 + tid * 8;
    __builtin_amdgcn_global_load_lds((gbl_void_t*)src, (lds_void_t*)dst, 16, 0, 0);
    __builtin_amdgcn_global_load_lds((gbl_void_t*)(src + 64L * FFN), (lds_void_t*)(dst + 4096), 16, 0, 0);
  };
  auto LDA8 = [&](bf16x8* a, int buf, int cb) {
    const char* base = (const char*)sh + buf * 65536 + wm * 16384 + l15 * 128 + cb;
#pragma unroll
    for (int m = 0; m < 8; ++m) a[m] = *(const bf16x8*)(base + m * 2048);
  };
  auto LDB2 = [&](bf16x8* b, int buf, int cb, int np) {
    const char* base = (const char*)sh + buf * 65536 + 32768 + (wn >> 1) * 16384 +
                       ((wn & 1) * 64 + l15) * 128 + cb;
    b[2 * np]     = *(const bf16x8*)(base + (2 * np) * 2048);
    b[2 * np + 1] = *(const bf16x8*)(base + (2 * np + 1) * 2048);
  };

  STAGE(0, 0, 0, 0); STAGE(0, 1, 0, 0); STAGE(1, 0, 0, 0); STAGE(1, 1, 0, 0);

  bf16x8 a[8], b[4];
  const int NT = FFN / 64;  // 224
  for (int t = 0; t < NT; ++t) {
    const int cur = t & 1, nxt = cur ^ 1;
    const bool pre = (t + 1 < NT);
    // ---- phase 0: prefetch A-half0(t+1); gate; kk0 x n{0,1}
    if (pre) { STAGE(0, 0, nxt, t + 1);
               asm volatile("s_waitcnt vmcnt(2)" ::: "memory"); }
    else     { asm volatile("s_waitcnt vmcnt(0)" ::: "memory"); }
    __builtin_amdgcn_s_barrier();
    __builtin_amdgcn_sched_barrier(0);
    LDA8(a, cur, cb0); LDB2(b, cur, cb0, 0);
    __builtin_amdgcn_s_setprio(1);
#pragma unroll
    for (int m = 0; m < 8; ++m) {
      acc[m][0] = MFMA16(a[m], b[0], acc[m][0]);
      acc[m][1] = MFMA16(a[m], b[1], acc[m][1]);
    }
    __builtin_amdgcn_s_setprio(0);
    __builtin_amdgcn_sched_barrier(0);
    asm volatile("s_waitcnt lgkmcnt(0)" ::: "memory");
    __builtin_amdgcn_s_barrier();
    // ---- phase 1: prefetch A-half1(t+1); kk0 x n{2,3}
    if (pre) STAGE(0, 1, nxt, t + 1);
    __builtin_amdgcn_sched_barrier(0);
    LDB2(b, cur, cb0, 1);
    __builtin_amdgcn_s_setprio(1);
#pragma unroll
    for (int m = 0; m < 8; ++m) {
      acc[m][2] = MFMA16(a[m], b[2], acc[m][2]);
      acc[m][3] = MFMA16(a[m], b[3], acc[m][3]);
    }
    __builtin_amdgcn_s_setprio(0);
    __builtin_amdgcn_sched_barrier(0);
    asm volatile("s_waitcnt lgkmcnt(0)" ::: "memory");
    __builtin_amdgcn_s_barrier();
    // ---- phase 2: prefetch B-half0(t+1); kk1 x n{0,1}
    if (pre) STAGE(1, 0, nxt, t + 1);
    __builtin_amdgcn_sched_barrier(0);
    LDA8(a, cur, cb1); LDB2(b, cur, cb1, 0);
    __builtin_amdgcn_s_setprio(1);
#pragma unroll
    for (int m = 0; m < 8; ++m) {
      acc[m][0] = MFMA16(a[m], b[0], acc[m][0]);
      acc[m][1] = MFMA16(a[m], b[1], acc[m][1]);
    }
    __builtin_amdgcn_s_setprio(0);
    __builtin_amdgcn_sched_barrier(0);
    asm volatile("s_waitcnt lgkmcnt(0)" ::: "memory");
    __builtin_amdgcn_s_barrier();
    // ---- phase 3: prefetch B-half1(t+1); kk1 x n{2,3}
    if (pre) STAGE(1, 1, nxt, t + 1);
    __builtin_amdgcn_sched_barrier(0);
    LDB2(b, cur, cb1, 1);
    __builtin_amdgcn_s_setprio(1);
#pragma unroll
    for (int m = 0; m < 8; ++m) {
      acc[m][2] = MFMA16(a[m], b[2], acc[m][2]);
      acc[m][3] = MFMA16(a[m], b[3], acc[m][3]);
    }
    __builtin_amdgcn_s_setprio(0);
    __builtin_amdgcn_sched_barrier(0);
    asm volatile("s_waitcnt lgkmcnt(0)" ::: "memory");
    __builtin_amdgcn_s_barrier();
  }
  const int r0 = (lane >> 4) * 4;
#pragma unroll
  for (int m = 0; m < 8; ++m)
#pragma unroll
    for (int n = 0; n < 4; ++n)
#pragma unroll
      for (int r = 0; r < 4; ++r) {
        const int row = bm * 256 + wm * 128 + m * 16 + r0 + r;
        const int col = bn * 256 + wn * 64 + n * 16 + l15;
        Out[(long)row * HIDDEN + col] = acc[m][n][r];
      }
}

// ---- fallback down (round-2 verified) when ws lacks w2t space ----
__device__ __forceinline__ void stage_tile_128(const unsigned short* __restrict__ g, long ldk,
                                               unsigned short* lds, int wave, int lane) {
#pragma unroll
  for (int it = 0; it < 2; ++it) {
    const int row = (it * 4 + wave) * 16 + (lane >> 2);
    const int kcol = (lane & 3) * 8;
    const unsigned short* src = g + (long)row * ldk + kcol;
    unsigned short* dst = lds + row * 32 + kcol;
    __builtin_amdgcn_global_load_lds((gbl_void_t*)src, (lds_void_t*)dst, 16, 0, 0);
  }
}

__global__ __launch_bounds__(256, 2)
void down_nt_kernel(const unsigned short* __restrict__ Inter,
                    const float* __restrict__ W2,
                    float* __restrict__ Out) {
  __shared__ unsigned short As[128 * 32];
  __shared__ unsigned short Bs[128 * 32];
  const int t = threadIdx.x;
  const int lane = t & 63;
  const int wave = t >> 6;
  const int bm = blockIdx.x & 31;
  const int bn = blockIdx.x >> 5;
  const int wm = (wave >> 1) * 64;
  const int wn = (wave & 1) * 64;
  const unsigned short* gA = Inter + (long)(bm * 128) * FFN;

  f32x4 acc[4][4] = {};
  const int fr = lane & 15;
  const int kg = (lane >> 4) * 8;
  const int p = lane & 15;
  const int h0 = wave * 32 + (lane >> 4) * 8;
  const float* gB = W2 + bn * 128 + h0;

  for (int kt = 0; kt < FFN; kt += 32) {
    __syncthreads();
    stage_tile_128(gA + kt, FFN, As, wave, lane);
    const float* r0p = gB + (long)(kt + 2 * p) * HIDDEN;
    const float* r1p = r0p + HIDDEN;
    const float4 a0 = *reinterpret_cast<const float4*>(r0p);
    const float4 a1 = *reinterpret_cast<const float4*>(r0p + 4);
    const float4 b0 = *reinterpret_cast<const float4*>(r1p);
    const float4 b1 = *reinterpret_cast<const float4*>(r1p + 4);
    unsigned short lo[8], hi[8];
    lo[0] = f2b(a0.x); lo[1] = f2b(a0.y); lo[2] = f2b(a0.z); lo[3] = f2b(a0.w);
    lo[4] = f2b(a1.x); lo[5] = f2b(a1.y); lo[6] = f2b(a1.z); lo[7] = f2b(a1.w);
    hi[0] = f2b(b0.x); hi[1] = f2b(b0.y); hi[2] = f2b(b0.z); hi[3] = f2b(b0.w);
    hi[4] = f2b(b1.x); hi[5] = f2b(b1.y); hi[6] = f2b(b1.z); hi[7] = f2b(b1.w);
#pragma unroll
    for (int j = 0; j < 8; ++j) {
      const unsigned int pack = (unsigned int)lo[j] | ((unsigned int)hi[j] << 16);
      *reinterpret_cast<unsigned int*>(&Bs[(h0 + j) * 32 + 2 * p]) = pack;
    }
    __syncthreads();
    bf16x8 a[4], b[4];
#pragma unroll
    for (int m = 0; m < 4; ++m)
      a[m] = *reinterpret_cast<const bf16x8*>(&As[(wm + m * 16 + fr) * 32 + kg]);
#pragma unroll
    for (int n = 0; n < 4; ++n)
      b[n] = *reinterpret_cast<const bf16x8*>(&Bs[(wn + n * 16 + fr) * 32 + kg]);
#pragma unroll
    for (int m = 0; m < 4; ++m)
#pragma unroll
      for (int n = 0; n < 4; ++n)
        acc[m][n] = MFMA16(a[m], b[n], acc[m][n]);
  }
  const int r0 = (lane >> 4) * 4;
#pragma unroll
  for (int m = 0; m < 4; ++m)
#pragma unroll
    for (int n = 0; n < 4; ++n)
#pragma unroll
      for (int r = 0; r < 4; ++r) {
        const int row = bm * 128 + wm + m * 16 + r0 + r;
        const int col = bn * 128 + wn + n * 16 + fr;
        Out[(long)row * HIDDEN + col] = acc[m][n][r];
      }
}

extern "C" void kernel_launch(void* const* d_in, const int* in_sizes, int n_in,
                              void* d_out, int out_size, void* d_ws, size_t ws_size,
                              hipStream_t stream) {
  const float* x  = (const float*)d_in[0];
  const float* w1 = (const float*)d_in[1];
  const float* v1 = (const float*)d_in[2];
  const float* w2 = (const float*)d_in[3];
  float* out = (float*)d_out;

  // ws layout (bytes): xb 33,554,432 | w1b 117,440,512 | v1b 117,440,512 |
  //                    inter 117,440,512 | w2t 117,440,512  -> 503,316,480 total.
  const size_t REQ_SMALL = 385875968UL;
  const size_t REQ_FULL  = 503316480UL;
  if (ws_size < REQ_SMALL) return;
  const bool full = (ws_size >= REQ_FULL);
  char* ws = (char*)d_ws;
  unsigned short* xb     = (unsigned short*)(ws);
  unsigned short* w1b    = (unsigned short*)(ws + 33554432L);
  unsigned short* v1b    = (unsigned short*)(ws + 150994944L);
  unsigned short* interb = (unsigned short*)(ws + 268435456L);
  unsigned short* w2tb   = (unsigned short*)(ws + 385875968L);

  hipLaunchKernelGGL(cvt_kernel, dim3(2048), dim3(256), 0, stream, x,  xb,  (long)TOKENS * HIDDEN);
  hipLaunchKernelGGL(cvt_kernel, dim3(2048), dim3(256), 0, stream, w1, w1b, (long)FFN * HIDDEN);
  hipLaunchKernelGGL(cvt_kernel, dim3(2048), dim3(256), 0, stream, v1, v1b, (long)FFN * HIDDEN);
  if (full)
    hipLaunchKernelGGL(transpose_cvt_kernel, dim3(FFN / 64, HIDDEN / 64), dim3(256), 0, stream, w2, w2tb);
  hipLaunchKernelGGL(gateup256_kernel, dim3((TOKENS / 256) * (FFN / 128)), dim3(512), 0, stream,
                     xb, w1b, v1b, interb);
  if (full)
    hipLaunchKernelGGL(down256_kernel, dim3((TOKENS / 256) * (HIDDEN / 256)), dim3(512), 0, stream,
                       interb, w2tb, out);
  else
    hipLaunchKernelGGL(down_nt_kernel, dim3((TOKENS / 128) * (HIDDEN / 128)), dim3(256), 0, stream,
                       interb, w2, out);
}

// Round 6
// 1426.490 us; speedup vs baseline: 1.5982x; 1.0348x over previous
//
#include <hip/hip_runtime.h>
#include <hip/hip_bf16.h>
#include <stdint.h>

// DbrxExpertGLU: down = (silu(x@w1^T) * (x@v1^T)) @ w2
// T=4096, H=4096, F=14336. fp32 in/out; bf16 MFMA compute.
// GEMMs: 256-tile 8-phase counted-vmcnt schedule (T2+T3+T4+T5).
// R6: stage-issue reorder — HBM-streamed operands (weights) issued with 4-phase
// lead, L3-hot operands 3-phase; single vmcnt(4) gate per K-tile at P0.
#define TOKENS 4096
#define HIDDEN 4096
#define FFN    14336

typedef __attribute__((ext_vector_type(8))) short bf16x8;
typedef __attribute__((ext_vector_type(4))) float f32x4;
typedef __attribute__((ext_vector_type(8))) unsigned short u16x8;

typedef __attribute__((address_space(3))) void lds_void_t;
typedef const __attribute__((address_space(1))) void gbl_void_t;

static __device__ __forceinline__ unsigned short f2b(float f) {
  union { float f; unsigned int u; } v; v.f = f;
  unsigned int u = v.u;
  return (unsigned short)((u + 0x7FFFu + ((u >> 16) & 1u)) >> 16);  // RNE
}

// ---------------- fp32 -> bf16 convert ----------------
__global__ void cvt_kernel(const float* __restrict__ in, unsigned short* __restrict__ out, long n) {
  long idx = (long)blockIdx.x * blockDim.x + threadIdx.x;
  long stride = (long)gridDim.x * blockDim.x;
  for (long i = idx * 4; i < n; i += stride * 4) {
    const float4 v = *reinterpret_cast<const float4*>(in + i);
    ushort4 o;
    o.x = f2b(v.x); o.y = f2b(v.y); o.z = f2b(v.z); o.w = f2b(v.w);
    *reinterpret_cast<ushort4*>(out + i) = o;
  }
}

// ------- w2 [F][H] fp32 -> w2t [H][F] bf16 -------
__global__ void transpose_cvt_kernel(const float* __restrict__ in, unsigned short* __restrict__ out) {
  __shared__ float tile[64][65];
  const int f0 = blockIdx.x * 64;
  const int h0 = blockIdx.y * 64;
  const int t = threadIdx.x;
  const int rcol = (t & 15) * 4;
  const int rrow = t >> 4;
#pragma unroll
  for (int it = 0; it < 4; ++it) {
    int r = rrow + it * 16;
    const float4 v = *reinterpret_cast<const float4*>(in + (long)(f0 + r) * HIDDEN + h0 + rcol);
    tile[r][rcol] = v.x; tile[r][rcol + 1] = v.y; tile[r][rcol + 2] = v.z; tile[r][rcol + 3] = v.w;
  }
  __syncthreads();
  const int wrow = t >> 2;
  const int wc = (t & 3) * 16;
  u16x8 lo, hi;
#pragma unroll
  for (int j = 0; j < 8; ++j) lo[j] = f2b(tile[wc + j][wrow]);
#pragma unroll
  for (int j = 0; j < 8; ++j) hi[j] = f2b(tile[wc + 8 + j][wrow]);
  u16x8* dst = reinterpret_cast<u16x8*>(out + (long)(h0 + wrow) * FFN + f0 + wc);
  dst[0] = lo; dst[1] = hi;
}

#define MFMA16(a, b, c) __builtin_amdgcn_mfma_f32_16x16x32_bf16((a), (b), (c), 0, 0, 0)

// ============ fused gate/up, 8-phase: BM=256(T) x BN=128(F), BK=64, 8 waves ============
// LDS per buf (64KB): A[256][64] @0 | W[128][64] @32K | V[128][64] @48K.  x2 dbuf = 128KB.
// Swizzle: byte_in_row ^= ((row&7)<<4); gload_lds dest linear, SOURCE pre-swizzled (rule #21).
__global__ __launch_bounds__(512, 2)
void gateup256_kernel(const unsigned short* __restrict__ X,
                      const unsigned short* __restrict__ W1,
                      const unsigned short* __restrict__ V1,
                      unsigned short* __restrict__ Inter) {
  __shared__ unsigned short sh[65536];  // 128 KB
  const int tid = threadIdx.x, lane = tid & 63, wid = tid >> 6;
  const int wm = wid >> 2, wn = wid & 3;
  const int bm = blockIdx.x & 15;   // T-tile fastest (L2/L3 weight-panel reuse)
  const int bn = blockIdx.x >> 4;   // F-tile
  const int sr = tid >> 3;                                   // staging row 0..63
  const int scb = (((tid & 7) ^ (sr & 7)) << 4);             // pre-swizzled src byte-col
  const int l15 = lane & 15;
  const int cb0 = (((lane >> 4) * 16) ^ ((lane & 7) << 4));  // frag byte-col, kk=0
  const int cb1 = ((64 + (lane >> 4) * 16) ^ ((lane & 7) << 4));

  const unsigned short* Ap = X  + (long)(bm * 256) * HIDDEN;
  const unsigned short* Wp = W1 + (long)(bn * 128) * HIDDEN;
  const unsigned short* Vp = V1 + (long)(bn * 128) * HIDDEN;

  f32x4 accg[8][2] = {};
  f32x4 accu[8][2] = {};

  auto STA = [&](int u, int buf, int t) {  // A unit u: rows u*64..+63, 8KB, 1 gload/thread
    const unsigned short* src = Ap + (long)(u * 64 + sr) * HIDDEN + t * 64 + (scb >> 1);
    unsigned short* dst = sh + buf * 32768 + u * 4096 + tid * 8;
    __builtin_amdgcn_global_load_lds((gbl_void_t*)src, (lds_void_t*)dst, 16, 0, 0);
  };
  auto STW = [&](int u, int buf, int t) {
    const unsigned short* src = Wp + (long)(u * 64 + sr) * HIDDEN + t * 64 + (scb >> 1);
    unsigned short* dst = sh + buf * 32768 + 16384 + u * 4096 + tid * 8;
    __builtin_amdgcn_global_load_lds((gbl_void_t*)src, (lds_void_t*)dst, 16, 0, 0);
  };
  auto STV = [&](int u, int buf, int t) {
    const unsigned short* src = Vp + (long)(u * 64 + sr) * HIDDEN + t * 64 + (scb >> 1);
    unsigned short* dst = sh + buf * 32768 + 24576 + u * 4096 + tid * 8;
    __builtin_amdgcn_global_load_lds((gbl_void_t*)src, (lds_void_t*)dst, 16, 0, 0);
  };
  auto LDA8 = [&](bf16x8* a, int buf, int cb) {
    const char* base = (const char*)sh + buf * 65536 + wm * 16384 + l15 * 128 + cb;
#pragma unroll
    for (int m = 0; m < 8; ++m) a[m] = *(const bf16x8*)(base + m * 2048);
  };
  auto LDW2 = [&](bf16x8* w, int buf, int cb) {
    const char* base = (const char*)sh + buf * 65536 + 32768 + (wn * 32 + l15) * 128 + cb;
    w[0] = *(const bf16x8*)(base);
    w[1] = *(const bf16x8*)(base + 2048);
  };
  auto LDV2 = [&](bf16x8* v, int buf, int cb) {
    const char* base = (const char*)sh + buf * 65536 + 49152 + (wn * 32 + l15) * 128 + cb;
    v[0] = *(const bf16x8*)(base);
    v[1] = *(const bf16x8*)(base + 2048);
  };

  // prologue: tile 0 fully staged into buf0 (8 loads/thread)
  STA(0, 0, 0); STA(1, 0, 0); STA(2, 0, 0); STA(3, 0, 0);
  STW(0, 0, 0); STW(1, 0, 0); STV(0, 0, 0); STV(1, 0, 0);

  bf16x8 a[8], w[2], v[2];
  const int NT = HIDDEN / 64;  // 64
  for (int t = 0; t < NT; ++t) {
    const int cur = t & 1, nxt = cur ^ 1;
    const bool pre = (t + 1 < NT);
    // ---- phase 0: prefetch W+V(t+1) (HBM-streamed, 4-phase lead); gate; kk0 x W
    if (pre) { STW(0, nxt, t + 1); STW(1, nxt, t + 1);
               STV(0, nxt, t + 1); STV(1, nxt, t + 1);
               asm volatile("s_waitcnt vmcnt(4)" ::: "memory"); }
    else     { asm volatile("s_waitcnt vmcnt(0)" ::: "memory"); }
    __builtin_amdgcn_s_barrier();
    __builtin_amdgcn_sched_barrier(0);
    LDA8(a, cur, cb0); LDW2(w, cur, cb0);
    __builtin_amdgcn_s_setprio(1);
#pragma unroll
    for (int m = 0; m < 8; ++m) {
      accg[m][0] = MFMA16(a[m], w[0], accg[m][0]);
      accg[m][1] = MFMA16(a[m], w[1], accg[m][1]);
    }
    __builtin_amdgcn_s_setprio(0);
    __builtin_amdgcn_sched_barrier(0);
    asm volatile("s_waitcnt lgkmcnt(0)" ::: "memory");
    __builtin_amdgcn_s_barrier();
    // ---- phase 1: prefetch A(t+1) (L3-hot X, 3-phase lead); kk0 x V
    if (pre) { STA(0, nxt, t + 1); STA(1, nxt, t + 1);
               STA(2, nxt, t + 1); STA(3, nxt, t + 1); }
    __builtin_amdgcn_sched_barrier(0);
    LDV2(v, cur, cb0);
    __builtin_amdgcn_s_setprio(1);
#pragma unroll
    for (int m = 0; m < 8; ++m) {
      accu[m][0] = MFMA16(a[m], v[0], accu[m][0]);
      accu[m][1] = MFMA16(a[m], v[1], accu[m][1]);
    }
    __builtin_amdgcn_s_setprio(0);
    __builtin_amdgcn_sched_barrier(0);
    asm volatile("s_waitcnt lgkmcnt(0)" ::: "memory");
    __builtin_amdgcn_s_barrier();
    // ---- phase 2: kk1 x W
    __builtin_amdgcn_sched_barrier(0);
    LDA8(a, cur, cb1); LDW2(w, cur, cb1);
    __builtin_amdgcn_s_setprio(1);
#pragma unroll
    for (int m = 0; m < 8; ++m) {
      accg[m][0] = MFMA16(a[m], w[0], accg[m][0]);
      accg[m][1] = MFMA16(a[m], w[1], accg[m][1]);
    }
    __builtin_amdgcn_s_setprio(0);
    __builtin_amdgcn_sched_barrier(0);
    asm volatile("s_waitcnt lgkmcnt(0)" ::: "memory");
    __builtin_amdgcn_s_barrier();
    // ---- phase 3: kk1 x V
    __builtin_amdgcn_sched_barrier(0);
    LDV2(v, cur, cb1);
    __builtin_amdgcn_s_setprio(1);
#pragma unroll
    for (int m = 0; m < 8; ++m) {
      accu[m][0] = MFMA16(a[m], v[0], accu[m][0]);
      accu[m][1] = MFMA16(a[m], v[1], accu[m][1]);
    }
    __builtin_amdgcn_s_setprio(0);
    __builtin_amdgcn_sched_barrier(0);
    asm volatile("s_waitcnt lgkmcnt(0)" ::: "memory");
    __builtin_amdgcn_s_barrier();
  }
  // epilogue: silu(g)*u -> bf16. C/D map: col=lane&15, row=(lane>>4)*4+r (m89)
  const int r0 = (lane >> 4) * 4;
#pragma unroll
  for (int m = 0; m < 8; ++m)
#pragma unroll
    for (int n = 0; n < 2; ++n)
#pragma unroll
      for (int r = 0; r < 4; ++r) {
        const float g = accg[m][n][r];
        const float u = accu[m][n][r];
        const float s = g / (1.0f + __expf(-g));
        const int row = bm * 256 + wm * 128 + m * 16 + r0 + r;
        const int col = bn * 128 + wn * 32 + n * 16 + l15;
        Inter[(long)row * FFN + col] = f2b(s * u);
      }
}

// ============ down GEMM-BT, 8-phase: 256x256, BK=64, 8 waves ============
// LDS per buf (64KB): A 2 halves [128][64] @0,@16K | B 2 halves @32K,@48K. x2 = 128KB.
__global__ __launch_bounds__(512, 2)
void down256_kernel(const unsigned short* __restrict__ Inter,
                    const unsigned short* __restrict__ W2t,
                    float* __restrict__ Out) {
  __shared__ unsigned short sh[65536];
  const int tid = threadIdx.x, lane = tid & 63, wid = tid >> 6;
  const int wm = wid >> 2, wn = wid & 3;
  const int bm = blockIdx.x & 15;   // T-tile fastest
  const int bn = blockIdx.x >> 4;   // H-tile
  const int sr = tid >> 3;
  const int scb = (((tid & 7) ^ (sr & 7)) << 4);
  const int l15 = lane & 15;
  const int cb0 = (((lane >> 4) * 16) ^ ((lane & 7) << 4));
  const int cb1 = ((64 + (lane >> 4) * 16) ^ ((lane & 7) << 4));

  const unsigned short* Ap = Inter + (long)(bm * 256) * FFN;
  const unsigned short* Bp = W2t + (long)(bn * 256) * FFN;

  f32x4 acc[8][4] = {};

  auto STAGE = [&](int kind, int h, int buf, int t) {  // half h: 128 rows, 2 gloads/thread
    const unsigned short* src = (kind ? Bp : Ap) + (long)(h * 128 + sr) * FFN + t * 64 + (scb >> 1);
    unsigned short* dst = sh + buf * 32768 + kind * 16384 + h * 8192 + tid * 8;
    __builtin_amdgcn_global_load_lds((gbl_void_t*)src, (lds_void_t*)dst, 16, 0, 0);
    __builtin_amdgcn_global_load_lds((gbl_void_t*)(src + 64L * FFN), (lds_void_t*)(dst + 4096), 16, 0, 0);
  };
  auto LDA8 = [&](bf16x8* a, int buf, int cb) {
    const char* base = (const char*)sh + buf * 65536 + wm * 16384 + l15 * 128 + cb;
#pragma unroll
    for (int m = 0; m < 8; ++m) a[m] = *(const bf16x8*)(base + m * 2048);
  };
  auto LDB2 = [&](bf16x8* b, int buf, int cb, int np) {
    const char* base = (const char*)sh + buf * 65536 + 32768 + (wn >> 1) * 16384 +
                       ((wn & 1) * 64 + l15) * 128 + cb;
    b[2 * np]     = *(const bf16x8*)(base + (2 * np) * 2048);
    b[2 * np + 1] = *(const bf16x8*)(base + (2 * np + 1) * 2048);
  };

  STAGE(0, 0, 0, 0); STAGE(0, 1, 0, 0); STAGE(1, 0, 0, 0); STAGE(1, 1, 0, 0);

  bf16x8 a[8], b[4];
  const int NT = FFN / 64;  // 224
  for (int t = 0; t < NT; ++t) {
    const int cur = t & 1, nxt = cur ^ 1;
    const bool pre = (t + 1 < NT);
    // ---- phase 0: prefetch B(t+1) both halves (HBM-streamed, 4-phase lead); gate; kk0 x n{0,1}
    if (pre) { STAGE(1, 0, nxt, t + 1); STAGE(1, 1, nxt, t + 1);
               asm volatile("s_waitcnt vmcnt(4)" ::: "memory"); }
    else     { asm volatile("s_waitcnt vmcnt(0)" ::: "memory"); }
    __builtin_amdgcn_s_barrier();
    __builtin_amdgcn_sched_barrier(0);
    LDA8(a, cur, cb0); LDB2(b, cur, cb0, 0);
    __builtin_amdgcn_s_setprio(1);
#pragma unroll
    for (int m = 0; m < 8; ++m) {
      acc[m][0] = MFMA16(a[m], b[0], acc[m][0]);
      acc[m][1] = MFMA16(a[m], b[1], acc[m][1]);
    }
    __builtin_amdgcn_s_setprio(0);
    __builtin_amdgcn_sched_barrier(0);
    asm volatile("s_waitcnt lgkmcnt(0)" ::: "memory");
    __builtin_amdgcn_s_barrier();
    // ---- phase 1: prefetch A(t+1) both halves (3-phase lead); kk0 x n{2,3}
    if (pre) { STAGE(0, 0, nxt, t + 1); STAGE(0, 1, nxt, t + 1); }
    __builtin_amdgcn_sched_barrier(0);
    LDB2(b, cur, cb0, 1);
    __builtin_amdgcn_s_setprio(1);
#pragma unroll
    for (int m = 0; m < 8; ++m) {
      acc[m][2] = MFMA16(a[m], b[2], acc[m][2]);
      acc[m][3] = MFMA16(a[m], b[3], acc[m][3]);
    }
    __builtin_amdgcn_s_setprio(0);
    __builtin_amdgcn_sched_barrier(0);
    asm volatile("s_waitcnt lgkmcnt(0)" ::: "memory");
    __builtin_amdgcn_s_barrier();
    // ---- phase 2: kk1 x n{0,1}
    __builtin_amdgcn_sched_barrier(0);
    LDA8(a, cur, cb1); LDB2(b, cur, cb1, 0);
    __builtin_amdgcn_s_setprio(1);
#pragma unroll
    for (int m = 0; m < 8; ++m) {
      acc[m][0] = MFMA16(a[m], b[0], acc[m][0]);
      acc[m][1] = MFMA16(a[m], b[1], acc[m][1]);
    }
    __builtin_amdgcn_s_setprio(0);
    __builtin_amdgcn_sched_barrier(0);
    asm volatile("s_waitcnt lgkmcnt(0)" ::: "memory");
    __builtin_amdgcn_s_barrier();
    // ---- phase 3: kk1 x n{2,3}
    __builtin_amdgcn_sched_barrier(0);
    LDB2(b, cur, cb1, 1);
    __builtin_amdgcn_s_setprio(1);
#pragma unroll
    for (int m = 0; m < 8; ++m) {
      acc[m][2] = MFMA16(a[m], b[2], acc[m][2]);
      acc[m][3] = MFMA16(a[m], b[3], acc[m][3]);
    }
    __builtin_amdgcn_s_setprio(0);
    __builtin_amdgcn_sched_barrier(0);
    asm volatile("s_waitcnt lgkmcnt(0)" ::: "memory");
    __builtin_amdgcn_s_barrier();
  }
  const int r0 = (lane >> 4) * 4;
#pragma unroll
  for (int m = 0; m < 8; ++m)
#pragma unroll
    for (int n = 0; n < 4; ++n)
#pragma unroll
      for (int r = 0; r < 4; ++r) {
        const int row = bm * 256 + wm * 128 + m * 16 + r0 + r;
        const int col = bn * 256 + wn * 64 + n * 16 + l15;
        Out[(long)row * HIDDEN + col] = acc[m][n][r];
      }
}

// ---- fallback down (round-2 verified) when ws lacks w2t space ----
__device__ __forceinline__ void stage_tile_128(const unsigned short* __restrict__ g, long ldk,
                                               unsigned short* lds, int wave, int lane) {
#pragma unroll
  for (int it = 0; it < 2; ++it) {
    const int row = (it * 4 + wave) * 16 + (lane >> 2);
    const int kcol = (lane & 3) * 8;
    const unsigned short* src = g + (long)row * ldk + kcol;
    unsigned short* dst = lds + row * 32 + kcol;
    __builtin_amdgcn_global_load_lds((gbl_void_t*)src, (lds_void_t*)dst, 16, 0, 0);
  }
}

__global__ __launch_bounds__(256, 2)
void down_nt_kernel(const unsigned short* __restrict__ Inter,
                    const float* __restrict__ W2,
                    float* __restrict__ Out) {
  __shared__ unsigned short As[128 * 32];
  __shared__ unsigned short Bs[128 * 32];
  const int t = threadIdx.x;
  const int lane = t & 63;
  const int wave = t >> 6;
  const int bm = blockIdx.x & 31;
  const int bn = blockIdx.x >> 5;
  const int wm = (wave >> 1) * 64;
  const int wn = (wave & 1) * 64;
  const unsigned short* gA = Inter + (long)(bm * 128) * FFN;

  f32x4 acc[4][4] = {};
  const int fr = lane & 15;
  const int kg = (lane >> 4) * 8;
  const int p = lane & 15;
  const int h0 = wave * 32 + (lane >> 4) * 8;
  const float* gB = W2 + bn * 128 + h0;

  for (int kt = 0; kt < FFN; kt += 32) {
    __syncthreads();
    stage_tile_128(gA + kt, FFN, As, wave, lane);
    const float* r0p = gB + (long)(kt + 2 * p) * HIDDEN;
    const float* r1p = r0p + HIDDEN;
    const float4 a0 = *reinterpret_cast<const float4*>(r0p);
    const float4 a1 = *reinterpret_cast<const float4*>(r0p + 4);
    const float4 b0 = *reinterpret_cast<const float4*>(r1p);
    const float4 b1 = *reinterpret_cast<const float4*>(r1p + 4);
    unsigned short lo[8], hi[8];
    lo[0] = f2b(a0.x); lo[1] = f2b(a0.y); lo[2] = f2b(a0.z); lo[3] = f2b(a0.w);
    lo[4] = f2b(a1.x); lo[5] = f2b(a1.y); lo[6] = f2b(a1.z); lo[7] = f2b(a1.w);
    hi[0] = f2b(b0.x); hi[1] = f2b(b0.y); hi[2] = f2b(b0.z); hi[3] = f2b(b0.w);
    hi[4] = f2b(b1.x); hi[5] = f2b(b1.y); hi[6] = f2b(b1.z); hi[7] = f2b(b1.w);
#pragma unroll
    for (int j = 0; j < 8; ++j) {
      const unsigned int pack = (unsigned int)lo[j] | ((unsigned int)hi[j] << 16);
      *reinterpret_cast<unsigned int*>(&Bs[(h0 + j) * 32 + 2 * p]) = pack;
    }
    __syncthreads();
    bf16x8 a[4], b[4];
#pragma unroll
    for (int m = 0; m < 4; ++m)
      a[m] = *reinterpret_cast<const bf16x8*>(&As[(wm + m * 16 + fr) * 32 + kg]);
#pragma unroll
    for (int n = 0; n < 4; ++n)
      b[n] = *reinterpret_cast<const bf16x8*>(&Bs[(wn + n * 16 + fr) * 32 + kg]);
#pragma unroll
    for (int m = 0; m < 4; ++m)
#pragma unroll
      for (int n = 0; n < 4; ++n)
        acc[m][n] = MFMA16(a[m], b[n], acc[m][n]);
  }
  const int r0 = (lane >> 4) * 4;
#pragma unroll
  for (int m = 0; m < 4; ++m)
#pragma unroll
    for (int n = 0; n < 4; ++n)
#pragma unroll
      for (int r = 0; r < 4; ++r) {
        const int row = bm * 128 + wm + m * 16 + r0 + r;
        const int col = bn * 128 + wn + n * 16 + fr;
        Out[(long)row * HIDDEN + col] = acc[m][n][r];
      }
}

extern "C" void kernel_launch(void* const* d_in, const int* in_sizes, int n_in,
                              void* d_out, int out_size, void* d_ws, size_t ws_size,
                              hipStream_t stream) {
  const float* x  = (const float*)d_in[0];
  const float* w1 = (const float*)d_in[1];
  const float* v1 = (const float*)d_in[2];
  const float* w2 = (const float*)d_in[3];
  float* out = (float*)d_out;

  // ws layout (bytes): xb 33,554,432 | w1b 117,440,512 | v1b 117,440,512 |
  //                    inter 117,440,512 | w2t 117,440,512  -> 503,316,480 total.
  const size_t REQ_SMALL = 385875968UL;
  const size_t REQ_FULL  = 503316480UL;
  if (ws_size < REQ_SMALL) return;
  const bool full = (ws_size >= REQ_FULL);
  char* ws = (char*)d_ws;
  unsigned short* xb     = (unsigned short*)(ws);
  unsigned short* w1b    = (unsigned short*)(ws + 33554432L);
  unsigned short* v1b    = (unsigned short*)(ws + 150994944L);
  unsigned short* interb = (unsigned short*)(ws + 268435456L);
  unsigned short* w2tb   = (unsigned short*)(ws + 385875968L);

  hipLaunchKernelGGL(cvt_kernel, dim3(2048), dim3(256), 0, stream, x,  xb,  (long)TOKENS * HIDDEN);
  hipLaunchKernelGGL(cvt_kernel, dim3(2048), dim3(256), 0, stream, w1, w1b, (long)FFN * HIDDEN);
  hipLaunchKernelGGL(cvt_kernel, dim3(2048), dim3(256), 0, stream, v1, v1b, (long)FFN * HIDDEN);
  if (full)
    hipLaunchKernelGGL(transpose_cvt_kernel, dim3(FFN / 64, HIDDEN / 64), dim3(256), 0, stream, w2, w2tb);
  hipLaunchKernelGGL(gateup256_kernel, dim3((TOKENS / 256) * (FFN / 128)), dim3(512), 0, stream,
                     xb, w1b, v1b, interb);
  if (full)
    hipLaunchKernelGGL(down256_kernel, dim3((TOKENS / 256) * (HIDDEN / 256)), dim3(512), 0, stream,
                       interb, w2tb, out);
  else
    hipLaunchKernelGGL(down_nt_kernel, dim3((TOKENS / 128) * (HIDDEN / 128)), dim3(256), 0, stream,
                       interb, w2, out);
}